// Round 16
// baseline (212.729 us; speedup 1.0000x reference)
//
#include <hip/hip_runtime.h>
#include <hip/hip_bf16.h>

typedef unsigned short u16;
typedef __bf16 bf16x8 __attribute__((ext_vector_type(8)));
typedef float f32x4 __attribute__((ext_vector_type(4)));
typedef unsigned short u16x4 __attribute__((ext_vector_type(4)));

#define MFMA16(a, b, c) __builtin_amdgcn_mfma_f32_16x16x32_bf16(a, b, c, 0, 0, 0)

__device__ __forceinline__ u16 f2bf(float f) {
  union { float f; unsigned u; } v; v.f = f;
  unsigned r = v.u + 0x7FFFu + ((v.u >> 16) & 1u);
  return (u16)(r >> 16);
}

__device__ __forceinline__ u16 f2bf_native(float f) {
  __hip_bfloat16 hb = __float2bfloat16(f);
  u16 out;
  __builtin_memcpy(&out, &hb, 2);
  return out;
}

__device__ __forceinline__ void gload16(const u16* g, u16* l) {
  __builtin_amdgcn_global_load_lds(
      (const __attribute__((address_space(1))) unsigned int*)g,
      (__attribute__((address_space(3))) unsigned int*)l, 16, 0, 0);
}

// ---------------- merged preamble: X f32->bf16 + Wq/Wk/Wv transpose-converts ----------------
__global__ __launch_bounds__(1024) void preamble(const float* __restrict__ X,
                                                 const float* __restrict__ Wq,
                                                 const float* __restrict__ Wk,
                                                 const float* __restrict__ Wv,
                                                 u16* __restrict__ Xb,
                                                 u16* __restrict__ WqT,
                                                 u16* __restrict__ WkT,
                                                 u16* __restrict__ WvT) {
  const int z = blockIdx.z;
  const int tx = threadIdx.x, ty = threadIdx.y;
  if (z == 3) {
    int bid = blockIdx.y * 64 + blockIdx.x;
    if (bid >= 2048) return;              // 2048 blocks x 1024 thr x 1 float4 = 8M f32
    int i = bid * 1024 + ty * 32 + tx;
    float4 v = ((const float4*)X)[i];
    u16x4 o = { f2bf(v.x), f2bf(v.y), f2bf(v.z), f2bf(v.w) };
    ((u16x4*)Xb)[i] = o;
    return;
  }
  const float* W; u16* WT; int N;
  if (z == 0)      { W = Wq; WT = WqT; N = 2048; }
  else if (z == 1) { W = Wk; WT = WkT; N = 512; }
  else             { W = Wv; WT = WvT; N = 512; }
  const int K = 2048;
  int n0 = blockIdx.x * 32;
  if (n0 >= N) return;
  int k0 = blockIdx.y * 32;
  __shared__ float t[32][33];
  t[ty][tx] = W[(size_t)(k0 + ty) * N + n0 + tx];
  __syncthreads();
  WT[(size_t)(n0 + ty) * K + k0 + tx] = f2bf(t[tx][ty]);
}

// ---------------- 4-wave 128x128 dbuf-prefetch GEMM (measured best; QKV) ----------------
// BM=BN=128, BK=32. 256 threads = 4 waves (2M x 2N), wave tile 64x64, acc 4x4.
// 32 KB LDS; prefetch: STAGE(t+1) -> ds_read(t) -> MFMA -> vmcnt(0) -> barrier.
// STORE: 4 = fused QKV: col<2048 -> Q bf16 *0.125 ; col<2560 -> K bf16 ; else V transposed
__device__ __forceinline__ void stage_tile4(const u16* __restrict__ A, const u16* __restrict__ BT,
                                            u16* la, u16* lb, int bm, int bn, int K, int k0, int tid) {
#pragma unroll
  for (int i = 0; i < 2; ++i) {
    int s = i * 256 + tid;
    int row = s >> 2;
    int c = (s & 3) ^ ((row >> 1) & 3);  // pre-swizzled global source (both-sides rule)
    gload16(A + (size_t)(bm + row) * K + k0 + c * 8, la + s * 8);
    gload16(BT + (size_t)(bn + row) * K + k0 + c * 8, lb + s * 8);
  }
}

template <int STORE>
__global__ __launch_bounds__(256) void gemm4(const u16* __restrict__ A,
                                             const u16* __restrict__ BT,
                                             void* __restrict__ Cv,
                                             int M, int N, int K) {
  __shared__ u16 lA[2][128 * 32];
  __shared__ u16 lB[2][128 * 32];
  const int tid = threadIdx.x;
  const int lane = tid & 63, wave = tid >> 6;
  const int gx = gridDim.x;
  const int nwg = gx * gridDim.y;
  const int bid = blockIdx.y * gx + blockIdx.x;
  const int sw = (bid & 7) * (nwg >> 3) + (bid >> 3);  // XCD chunk swizzle (nwg % 8 == 0)
  const int bx = sw % gx, by = sw / gx;
  const int bm = by * 128, bn = bx * 128;
  const int wm = (wave >> 1) * 64, wn = (wave & 1) * 64;
  const int l15 = lane & 15, l4 = lane >> 4;

  f32x4 acc[4][4] = {};

  u16* ra = (u16*)lA[0]; u16* rb = (u16*)lB[0];
  u16* wa = (u16*)lA[1]; u16* wb = (u16*)lB[1];

  stage_tile4(A, BT, ra, rb, bm, bn, K, 0, tid);
  asm volatile("s_waitcnt vmcnt(0)" ::: "memory");
  __builtin_amdgcn_s_barrier();

  const int NT = K >> 5;
#pragma unroll 1
  for (int t = 0; t < NT; ++t) {
    if (t + 1 < NT) stage_tile4(A, BT, wa, wb, bm, bn, K, (t + 1) << 5, tid);
    bf16x8 af[4], bf[4];
#pragma unroll
    for (int i = 0; i < 4; ++i) {
      int r = wm + i * 16 + l15;
      af[i] = *(const bf16x8*)&ra[r * 32 + (l4 ^ ((r >> 1) & 3)) * 8];
      int n = wn + i * 16 + l15;
      bf[i] = *(const bf16x8*)&rb[n * 32 + (l4 ^ ((n >> 1) & 3)) * 8];
    }
    __builtin_amdgcn_s_setprio(1);
#pragma unroll
    for (int i = 0; i < 4; ++i)
#pragma unroll
      for (int j = 0; j < 4; ++j)
        acc[i][j] = MFMA16(af[i], bf[j], acc[i][j]);
    __builtin_amdgcn_s_setprio(0);
    asm volatile("s_waitcnt vmcnt(0)" ::: "memory");
    __builtin_amdgcn_s_barrier();
    u16* t1 = ra; ra = wa; wa = t1;
    u16* t2 = rb; rb = wb; wb = t2;
  }

#pragma unroll
  for (int i = 0; i < 4; ++i) {
    int row = bm + wm + i * 16 + l4 * 4;
#pragma unroll
    for (int j = 0; j < 4; ++j) {
      int col = bn + wn + j * 16 + l15;
#pragma unroll
      for (int e = 0; e < 4; ++e) {
        float v = acc[i][j][e];
        if (STORE == 2) {
          ((float*)Cv)[(size_t)(row + e) * N + col] = v;
        } else {  // STORE == 4, fused QKV
          u16* Qb = (u16*)Cv;
          u16* Kb = Qb + 8388608;
          u16* Vt = Kb + 2097152;
          if (col < 2048)       Qb[(size_t)(row + e) * 2048 + col] = f2bf(v * 0.125f);
          else if (col < 2560)  Kb[(size_t)(row + e) * 512 + (col - 2048)] = f2bf(v);
          else                  Vt[(size_t)(col - 2560) * 4096 + (row + e)] = f2bf(v);
        }
      }
    }
  }
}

// ---------------- thin-tile GEMM for Wo: BM=128, BN=64 -> 1024 blocks = 4/CU ----------------
// Discriminating experiment: wave-law predicts ~912 TF (16 waves/CU); congestion predicts null.
// 256 thr = 4 waves (2M x 2N), wave tile 64x32, acc[4][2]. LDS 24 KB (2 buffers).
// Same prefetch schedule / swizzle / T1 as gemm4. f32 row-major store.
__device__ __forceinline__ void stage_thin(const u16* __restrict__ A, const u16* __restrict__ BT,
                                           u16* la, u16* lb, int bm, int bn, int K, int k0, int tid) {
#pragma unroll
  for (int i = 0; i < 2; ++i) {
    int s = i * 256 + tid;
    int row = s >> 2;
    int c = (s & 3) ^ ((row >> 1) & 3);
    gload16(A + (size_t)(bm + row) * K + k0 + c * 8, la + s * 8);
  }
  {
    int row = tid >> 2;                       // 64 B rows
    int c = (tid & 3) ^ ((row >> 1) & 3);
    gload16(BT + (size_t)(bn + row) * K + k0 + c * 8, lb + tid * 8);
  }
}

__global__ __launch_bounds__(256) void gemm_thin(const u16* __restrict__ A,
                                                 const u16* __restrict__ BT,
                                                 float* __restrict__ C,
                                                 int M, int N, int K) {
  __shared__ u16 lA[2][128 * 32];
  __shared__ u16 lB[2][64 * 32];
  const int tid = threadIdx.x;
  const int lane = tid & 63, wave = tid >> 6;
  const int gx = gridDim.x;
  const int nwg = gx * gridDim.y;
  const int bid = blockIdx.y * gx + blockIdx.x;
  const int sw = (bid & 7) * (nwg >> 3) + (bid >> 3);  // XCD chunk swizzle (nwg % 8 == 0)
  const int bx = sw % gx, by = sw / gx;
  const int bm = by * 128, bn = bx * 64;
  const int wm = (wave >> 1) * 64, wn = (wave & 1) * 32;
  const int l15 = lane & 15, l4 = lane >> 4;

  f32x4 acc[4][2] = {};

  u16* ra = (u16*)lA[0]; u16* rb = (u16*)lB[0];
  u16* wa = (u16*)lA[1]; u16* wb = (u16*)lB[1];

  stage_thin(A, BT, ra, rb, bm, bn, K, 0, tid);
  asm volatile("s_waitcnt vmcnt(0)" ::: "memory");
  __builtin_amdgcn_s_barrier();

  const int NT = K >> 5;
#pragma unroll 1
  for (int t = 0; t < NT; ++t) {
    if (t + 1 < NT) stage_thin(A, BT, wa, wb, bm, bn, K, (t + 1) << 5, tid);
    bf16x8 af[4], bf[2];
#pragma unroll
    for (int i = 0; i < 4; ++i) {
      int r = wm + i * 16 + l15;
      af[i] = *(const bf16x8*)&ra[r * 32 + (l4 ^ ((r >> 1) & 3)) * 8];
    }
#pragma unroll
    for (int j = 0; j < 2; ++j) {
      int n = wn + j * 16 + l15;
      bf[j] = *(const bf16x8*)&rb[n * 32 + (l4 ^ ((n >> 1) & 3)) * 8];
    }
    __builtin_amdgcn_s_setprio(1);
#pragma unroll
    for (int i = 0; i < 4; ++i)
#pragma unroll
      for (int j = 0; j < 2; ++j)
        acc[i][j] = MFMA16(af[i], bf[j], acc[i][j]);
    __builtin_amdgcn_s_setprio(0);
    asm volatile("s_waitcnt vmcnt(0)" ::: "memory");
    __builtin_amdgcn_s_barrier();
    u16* t1 = ra; ra = wa; wa = t1;
    u16* t2 = rb; rb = wb; wb = t2;
  }

#pragma unroll
  for (int i = 0; i < 4; ++i) {
    int row = bm + wm + i * 16 + l4 * 4;
#pragma unroll
    for (int j = 0; j < 2; ++j) {
      int col = bn + wn + j * 16 + l15;
#pragma unroll
      for (int e = 0; e < 4; ++e)
        C[(size_t)(row + e) * N + col] = acc[i][j][e];
    }
  }
}

// ---------------- causal flash attention + hidden WoT transpose ----------------
// grid (32, 8, 3): z=0,1 attention (b=z); z=2 Wo transpose (rides under attn).
__global__ __launch_bounds__(512) void attn_fwd(const u16* __restrict__ Q,
                                                const u16* __restrict__ Kb,
                                                const u16* __restrict__ VT,
                                                u16* __restrict__ AO,
                                                const float* __restrict__ Wo,
                                                u16* __restrict__ WoT) {
  __shared__ u16 Klds[2][64 * 64];   // [t][d], chunk-XOR swizzled (z=2: aliased as f32 scratch)
  __shared__ u16 Vlds[2][64 * 64];   // [d][t], chunk-XOR swizzled
  __shared__ u16 Plds[8][16 * 64];   // per-wave P, [q][t], 16B-slot XOR swizzled

  const int tid = threadIdx.x;

  if (blockIdx.z == 2) {
    float (*ts)[33] = (float (*)[33])Klds;   // 32x33 f32 scratch
    const int tx = tid & 31, ty = tid >> 5;  // ty in [0,16)
    const int bid = blockIdx.y * 32 + blockIdx.x;
#pragma unroll 1
    for (int ti = 0; ti < 16; ++ti) {
      int tile = bid * 16 + ti;
      int n0 = (tile & 63) * 32, k0 = (tile >> 6) * 32;
      ts[ty][tx]      = Wo[(size_t)(k0 + ty) * 2048 + n0 + tx];
      ts[ty + 16][tx] = Wo[(size_t)(k0 + ty + 16) * 2048 + n0 + tx];
      __syncthreads();
      WoT[(size_t)(n0 + ty) * 2048 + k0 + tx]      = f2bf(ts[tx][ty]);
      WoT[(size_t)(n0 + ty + 16) * 2048 + k0 + tx] = f2bf(ts[tx][ty + 16]);
      __syncthreads();
    }
    return;
  }

  const int pair = blockIdx.x, g = blockIdx.y, b = blockIdx.z;
  const int lane = tid & 63;
  const int wave = tid >> 6;
  const int a = wave >> 1;                  // head sub-index, h = a*8+g
  const int h = a * 8 + g;
  const int l15 = lane & 15, l4 = lane >> 4;

  const int srow = tid >> 3, sc = (tid & 7) ^ (srow & 7);

  int cur = 0;
#pragma unroll 1
  for (int pass = 0; pass < 2; ++pass) {
    const int qt = (pass == 0) ? pair : 63 - pair;
    const int qw0 = qt * 32 + (wave & 1) * 16;
    const int nt = qt / 2 + 1;

    const u16* qp = Q + (size_t)(b * 2048 + qw0 + l15) * 2048 + h * 64 + l4 * 8;
    bf16x8 qf0 = *(const bf16x8*)qp;
    bf16x8 qf1 = *(const bf16x8*)(qp + 32);

    float m_r = -1e30f, l_r = 0.f;
    f32x4 o[4] = {};

    {
      gload16(Kb + (size_t)(b * 2048 + 0 + srow) * 512 + g * 64 + sc * 8, &Klds[cur][tid * 8]);
      gload16(VT + (size_t)(g * 64 + srow) * 4096 + b * 2048 + 0 + sc * 8, &Vlds[cur][tid * 8]);
      asm volatile("s_waitcnt vmcnt(0)" ::: "memory");
      __builtin_amdgcn_s_barrier();
    }

#pragma unroll 1
    for (int ti = 0; ti < nt; ++ti) {
      const int t0 = ti * 64;
      if (ti + 1 < nt) {
        const int tn = t0 + 64;
        gload16(Kb + (size_t)(b * 2048 + tn + srow) * 512 + g * 64 + sc * 8, &Klds[cur ^ 1][tid * 8]);
        gload16(VT + (size_t)(g * 64 + srow) * 4096 + b * 2048 + tn + sc * 8, &Vlds[cur ^ 1][tid * 8]);
      }

      if (t0 <= qw0 + 15) {
        const u16* Kc = Klds[cur];
        const u16* Vc = Vlds[cur];
        f32x4 s[4];
        __builtin_amdgcn_s_setprio(1);
#pragma unroll
        for (int ct = 0; ct < 4; ++ct) {
          int t = ct * 16 + l15;
          bf16x8 kf0 = *(const bf16x8*)&Kc[(t * 8 + (l4 ^ (t & 7))) * 8];
          bf16x8 kf1 = *(const bf16x8*)&Kc[(t * 8 + ((l4 + 4) ^ (t & 7))) * 8];
          f32x4 sv = {0.f, 0.f, 0.f, 0.f};
          sv = MFMA16(kf0, qf0, sv);   // swapped: S[t][q]
          sv = MFMA16(kf1, qf1, sv);
          s[ct] = sv;
        }
        __builtin_amdgcn_s_setprio(0);

        if (t0 + 63 > qw0) {
          const int qg = qw0 + l15;
#pragma unroll
          for (int ct = 0; ct < 4; ++ct)
#pragma unroll
            for (int e = 0; e < 4; ++e) {
              int tg = t0 + ct * 16 + l4 * 4 + e;
              if (tg > qg) s[ct][e] = -1e30f;
            }
        }

        float m0 = fmaxf(fmaxf(s[0][0], s[0][1]), fmaxf(s[0][2], s[0][3]));
        float m1 = fmaxf(fmaxf(s[1][0], s[1][1]), fmaxf(s[1][2], s[1][3]));
        float m2 = fmaxf(fmaxf(s[2][0], s[2][1]), fmaxf(s[2][2], s[2][3]));
        float m3 = fmaxf(fmaxf(s[3][0], s[3][1]), fmaxf(s[3][2], s[3][3]));
        float mt = fmaxf(fmaxf(m0, m1), fmaxf(m2, m3));
        mt = fmaxf(mt, __shfl_xor(mt, 16));
        mt = fmaxf(mt, __shfl_xor(mt, 32));

        if (!__all(mt <= m_r + 8.0f)) {
          float mn = fmaxf(m_r, mt);
          float alpha = __expf(m_r - mn);
          m_r = mn;
          l_r *= alpha;
#pragma unroll
          for (int e = 0; e < 4; ++e) {
            float ae = __shfl(alpha, l4 * 4 + e);
            o[0][e] *= ae; o[1][e] *= ae; o[2][e] *= ae; o[3][e] *= ae;
          }
        }

        u16* P = Plds[wave];
        float rs = 0.f;
#pragma unroll
        for (int ct = 0; ct < 4; ++ct) {
          u16x4 pk;
#pragma unroll
          for (int e = 0; e < 4; ++e) {
            float p = __expf(s[ct][e] - m_r);
            rs += p;
            pk[e] = f2bf_native(p);
          }
          int slot = (ct * 2 + (l4 >> 1)) ^ (l15 & 7);
          *(u16x4*)&P[l15 * 64 + slot * 8 + (l4 & 1) * 4] = pk;
        }
        rs += __shfl_xor(rs, 16);
        rs += __shfl_xor(rs, 32);
        l_r += rs;

        __builtin_amdgcn_s_setprio(1);
#pragma unroll
        for (int kk = 0; kk < 2; ++kk) {
          bf16x8 pf = *(const bf16x8*)&P[l15 * 64 + (((kk * 4 + l4) ^ (l15 & 7)) * 8)];
#pragma unroll
          for (int cd = 0; cd < 4; ++cd) {
            int d = cd * 16 + l15;
            bf16x8 vf = *(const bf16x8*)&Vc[(d * 8 + ((kk * 4 + l4) ^ (d & 7))) * 8];
            o[cd] = MFMA16(pf, vf, o[cd]);
          }
        }
        __builtin_amdgcn_s_setprio(0);
      }

      asm volatile("s_waitcnt vmcnt(0)" ::: "memory");
      __builtin_amdgcn_s_barrier();
      cur ^= 1;
    }

    float rli = 1.0f / l_r;
#pragma unroll
    for (int cd = 0; cd < 4; ++cd)
#pragma unroll
      for (int e = 0; e < 4; ++e) {
        float rle = __shfl(rli, l4 * 4 + e);
        int r = l4 * 4 + e;
        int d = cd * 16 + l15;
        AO[(size_t)(b * 2048 + qw0 + r) * 2048 + h * 64 + d] = f2bf_native(o[cd][e] * rle);
      }
  }
}

// ---------------- launcher ----------------
extern "C" void kernel_launch(void* const* d_in, const int* in_sizes, int n_in,
                              void* d_out, int out_size, void* d_ws, size_t ws_size,
                              hipStream_t stream) {
  const float* X  = (const float*)d_in[0];
  const float* Wq = (const float*)d_in[1];
  const float* Wk = (const float*)d_in[2];
  const float* Wv = (const float*)d_in[3];
  const float* Wo = (const float*)d_in[4];
  float* out = (float*)d_out;

  u16* ws  = (u16*)d_ws;
  u16* Xb  = ws;                 // 8,388,608 elems  [4096][2048]
  u16* WqT = Xb  + 8388608;      // 4,194,304  [2048][2048] -- WqT,WkT,WvT contiguous [3072][2048]
  u16* WkT = WqT + 4194304;      // 1,048,576  [512][2048]
  u16* WvT = WkT + 1048576;      // 1,048,576  [512][2048]
  u16* WoT = WvT + 1048576;      // 4,194,304  [2048][2048]
  u16* Qb  = WoT + 4194304;      // 8,388,608  [4096][2048]  (pre-scaled by 0.125)
  u16* Kbf = Qb  + 8388608;      // 2,097,152  [4096][512]
  u16* VTb = Kbf + 2097152;      // 2,097,152  [512][4096]
  u16* AOb = Xb;                 // alias X after projections are done

  // preamble: X cvt + Wq/Wk/Wv transposes (WoT rides under attn)
  preamble<<<dim3(64, 64, 4), dim3(32, 32), 0, stream>>>(X, Wq, Wk, Wv,
                                                         Xb, WqT, WkT, WvT);

  // fused QKV projection: BT = [WqT; WkT; WvT] (contiguous), N = 3072, grid 24x32 = 768 blocks
  gemm4<4><<<dim3(24, 32), 256, 0, stream>>>(Xb, WqT, Qb, 4096, 3072, 2048);

  // attention (z=0,1) + hidden WoT transpose (z=2)
  attn_fwd<<<dim3(32, 8, 3), 512, 0, stream>>>(Qb, Kbf, VTb, AOb, Wo, WoT);

  // output projection, thin tiles: grid 32x32 = 1024 blocks -> 4 blocks/CU (16 waves/CU)
  gemm_thin<<<dim3(32, 32), 256, 0, stream>>>(AOb, WoT, out, 4096, 2048, 2048);
}

// Round 17
// 208.663 us; speedup vs baseline: 1.0195x; 1.0195x over previous
//
#include <hip/hip_runtime.h>
#include <hip/hip_bf16.h>

typedef unsigned short u16;
typedef __bf16 bf16x8 __attribute__((ext_vector_type(8)));
typedef float f32x4 __attribute__((ext_vector_type(4)));
typedef unsigned short u16x4 __attribute__((ext_vector_type(4)));

#define MFMA16(a, b, c) __builtin_amdgcn_mfma_f32_16x16x32_bf16(a, b, c, 0, 0, 0)

__device__ __forceinline__ u16 f2bf(float f) {
  union { float f; unsigned u; } v; v.f = f;
  unsigned r = v.u + 0x7FFFu + ((v.u >> 16) & 1u);
  return (u16)(r >> 16);
}

__device__ __forceinline__ u16 f2bf_native(float f) {
  __hip_bfloat16 hb = __float2bfloat16(f);
  u16 out;
  __builtin_memcpy(&out, &hb, 2);
  return out;
}

__device__ __forceinline__ void gload16(const u16* g, u16* l) {
  __builtin_amdgcn_global_load_lds(
      (const __attribute__((address_space(1))) unsigned int*)g,
      (__attribute__((address_space(3))) unsigned int*)l, 16, 0, 0);
}

// ---------------- merged preamble: X f32->bf16 + Wq/Wk/Wv transpose-converts ----------------
__global__ __launch_bounds__(1024) void preamble(const float* __restrict__ X,
                                                 const float* __restrict__ Wq,
                                                 const float* __restrict__ Wk,
                                                 const float* __restrict__ Wv,
                                                 u16* __restrict__ Xb,
                                                 u16* __restrict__ WqT,
                                                 u16* __restrict__ WkT,
                                                 u16* __restrict__ WvT) {
  const int z = blockIdx.z;
  const int tx = threadIdx.x, ty = threadIdx.y;
  if (z == 3) {
    int bid = blockIdx.y * 64 + blockIdx.x;
    if (bid >= 2048) return;              // 2048 blocks x 1024 thr x 1 float4 = 8M f32
    int i = bid * 1024 + ty * 32 + tx;
    float4 v = ((const float4*)X)[i];
    u16x4 o = { f2bf(v.x), f2bf(v.y), f2bf(v.z), f2bf(v.w) };
    ((u16x4*)Xb)[i] = o;
    return;
  }
  const float* W; u16* WT; int N;
  if (z == 0)      { W = Wq; WT = WqT; N = 2048; }
  else if (z == 1) { W = Wk; WT = WkT; N = 512; }
  else             { W = Wv; WT = WvT; N = 512; }
  const int K = 2048;
  int n0 = blockIdx.x * 32;
  if (n0 >= N) return;
  int k0 = blockIdx.y * 32;
  __shared__ float t[32][33];
  t[ty][tx] = W[(size_t)(k0 + ty) * N + n0 + tx];
  __syncthreads();
  WT[(size_t)(n0 + ty) * K + k0 + tx] = f2bf(t[tx][ty]);
}

// ---------------- 4-wave 128x128 dbuf-prefetch GEMM (measured best: R12/R14/R15) ----------------
// BM=BN=128, BK=32. 256 threads = 4 waves (2M x 2N), wave tile 64x64, acc 4x4.
// 32 KB LDS; prefetch: STAGE(t+1) -> ds_read(t) -> MFMA -> vmcnt(0) -> barrier.
// Session law: per-wave latency cap saturating ~12 waves/CU (thin-tile/split-K both null);
// this config maximizes useful residency. T1 XCD chunk swizzle (%8==0 grids).
// STORE: 2 = f32 row-major [M][N]
// STORE: 4 = fused QKV: col<2048 -> Q bf16 *0.125 ; col<2560 -> K bf16 ; else V transposed
__device__ __forceinline__ void stage_tile4(const u16* __restrict__ A, const u16* __restrict__ BT,
                                            u16* la, u16* lb, int bm, int bn, int K, int k0, int tid) {
#pragma unroll
  for (int i = 0; i < 2; ++i) {
    int s = i * 256 + tid;
    int row = s >> 2;
    int c = (s & 3) ^ ((row >> 1) & 3);  // pre-swizzled global source (both-sides rule)
    gload16(A + (size_t)(bm + row) * K + k0 + c * 8, la + s * 8);
    gload16(BT + (size_t)(bn + row) * K + k0 + c * 8, lb + s * 8);
  }
}

template <int STORE>
__global__ __launch_bounds__(256) void gemm4(const u16* __restrict__ A,
                                             const u16* __restrict__ BT,
                                             void* __restrict__ Cv,
                                             int M, int N, int K) {
  __shared__ u16 lA[2][128 * 32];
  __shared__ u16 lB[2][128 * 32];
  const int tid = threadIdx.x;
  const int lane = tid & 63, wave = tid >> 6;
  const int gx = gridDim.x;
  const int nwg = gx * gridDim.y;
  const int bid = blockIdx.y * gx + blockIdx.x;
  const int sw = (bid & 7) * (nwg >> 3) + (bid >> 3);  // XCD chunk swizzle (nwg % 8 == 0)
  const int bx = sw % gx, by = sw / gx;
  const int bm = by * 128, bn = bx * 128;
  const int wm = (wave >> 1) * 64, wn = (wave & 1) * 64;
  const int l15 = lane & 15, l4 = lane >> 4;

  f32x4 acc[4][4] = {};

  u16* ra = (u16*)lA[0]; u16* rb = (u16*)lB[0];
  u16* wa = (u16*)lA[1]; u16* wb = (u16*)lB[1];

  stage_tile4(A, BT, ra, rb, bm, bn, K, 0, tid);
  asm volatile("s_waitcnt vmcnt(0)" ::: "memory");
  __builtin_amdgcn_s_barrier();

  const int NT = K >> 5;
#pragma unroll 1
  for (int t = 0; t < NT; ++t) {
    if (t + 1 < NT) stage_tile4(A, BT, wa, wb, bm, bn, K, (t + 1) << 5, tid);
    bf16x8 af[4], bf[4];
#pragma unroll
    for (int i = 0; i < 4; ++i) {
      int r = wm + i * 16 + l15;
      af[i] = *(const bf16x8*)&ra[r * 32 + (l4 ^ ((r >> 1) & 3)) * 8];
      int n = wn + i * 16 + l15;
      bf[i] = *(const bf16x8*)&rb[n * 32 + (l4 ^ ((n >> 1) & 3)) * 8];
    }
    __builtin_amdgcn_s_setprio(1);
#pragma unroll
    for (int i = 0; i < 4; ++i)
#pragma unroll
      for (int j = 0; j < 4; ++j)
        acc[i][j] = MFMA16(af[i], bf[j], acc[i][j]);
    __builtin_amdgcn_s_setprio(0);
    asm volatile("s_waitcnt vmcnt(0)" ::: "memory");
    __builtin_amdgcn_s_barrier();
    u16* t1 = ra; ra = wa; wa = t1;
    u16* t2 = rb; rb = wb; wb = t2;
  }

#pragma unroll
  for (int i = 0; i < 4; ++i) {
    int row = bm + wm + i * 16 + l4 * 4;
#pragma unroll
    for (int j = 0; j < 4; ++j) {
      int col = bn + wn + j * 16 + l15;
#pragma unroll
      for (int e = 0; e < 4; ++e) {
        float v = acc[i][j][e];
        if (STORE == 2) {
          ((float*)Cv)[(size_t)(row + e) * N + col] = v;
        } else {  // STORE == 4, fused QKV
          u16* Qb = (u16*)Cv;
          u16* Kb = Qb + 8388608;
          u16* Vt = Kb + 2097152;
          if (col < 2048)       Qb[(size_t)(row + e) * 2048 + col] = f2bf(v * 0.125f);
          else if (col < 2560)  Kb[(size_t)(row + e) * 512 + (col - 2048)] = f2bf(v);
          else                  Vt[(size_t)(col - 2560) * 4096 + (row + e)] = f2bf(v);
        }
      }
    }
  }
}

// ---------------- causal flash attention + hidden WoT transpose ----------------
// grid (32, 8, 3): z=0,1 attention (b=z); z=2 Wo transpose (rides under attn).
__global__ __launch_bounds__(512) void attn_fwd(const u16* __restrict__ Q,
                                                const u16* __restrict__ Kb,
                                                const u16* __restrict__ VT,
                                                u16* __restrict__ AO,
                                                const float* __restrict__ Wo,
                                                u16* __restrict__ WoT) {
  __shared__ u16 Klds[2][64 * 64];   // [t][d], chunk-XOR swizzled (z=2: aliased as f32 scratch)
  __shared__ u16 Vlds[2][64 * 64];   // [d][t], chunk-XOR swizzled
  __shared__ u16 Plds[8][16 * 64];   // per-wave P, [q][t], 16B-slot XOR swizzled

  const int tid = threadIdx.x;

  if (blockIdx.z == 2) {
    float (*ts)[33] = (float (*)[33])Klds;   // 32x33 f32 scratch
    const int tx = tid & 31, ty = tid >> 5;  // ty in [0,16)
    const int bid = blockIdx.y * 32 + blockIdx.x;
#pragma unroll 1
    for (int ti = 0; ti < 16; ++ti) {
      int tile = bid * 16 + ti;
      int n0 = (tile & 63) * 32, k0 = (tile >> 6) * 32;
      ts[ty][tx]      = Wo[(size_t)(k0 + ty) * 2048 + n0 + tx];
      ts[ty + 16][tx] = Wo[(size_t)(k0 + ty + 16) * 2048 + n0 + tx];
      __syncthreads();
      WoT[(size_t)(n0 + ty) * 2048 + k0 + tx]      = f2bf(ts[tx][ty]);
      WoT[(size_t)(n0 + ty + 16) * 2048 + k0 + tx] = f2bf(ts[tx][ty + 16]);
      __syncthreads();
    }
    return;
  }

  const int pair = blockIdx.x, g = blockIdx.y, b = blockIdx.z;
  const int lane = tid & 63;
  const int wave = tid >> 6;
  const int a = wave >> 1;                  // head sub-index, h = a*8+g
  const int h = a * 8 + g;
  const int l15 = lane & 15, l4 = lane >> 4;

  const int srow = tid >> 3, sc = (tid & 7) ^ (srow & 7);

  int cur = 0;
#pragma unroll 1
  for (int pass = 0; pass < 2; ++pass) {
    const int qt = (pass == 0) ? pair : 63 - pair;
    const int qw0 = qt * 32 + (wave & 1) * 16;
    const int nt = qt / 2 + 1;

    const u16* qp = Q + (size_t)(b * 2048 + qw0 + l15) * 2048 + h * 64 + l4 * 8;
    bf16x8 qf0 = *(const bf16x8*)qp;
    bf16x8 qf1 = *(const bf16x8*)(qp + 32);

    float m_r = -1e30f, l_r = 0.f;
    f32x4 o[4] = {};

    {
      gload16(Kb + (size_t)(b * 2048 + 0 + srow) * 512 + g * 64 + sc * 8, &Klds[cur][tid * 8]);
      gload16(VT + (size_t)(g * 64 + srow) * 4096 + b * 2048 + 0 + sc * 8, &Vlds[cur][tid * 8]);
      asm volatile("s_waitcnt vmcnt(0)" ::: "memory");
      __builtin_amdgcn_s_barrier();
    }

#pragma unroll 1
    for (int ti = 0; ti < nt; ++ti) {
      const int t0 = ti * 64;
      if (ti + 1 < nt) {
        const int tn = t0 + 64;
        gload16(Kb + (size_t)(b * 2048 + tn + srow) * 512 + g * 64 + sc * 8, &Klds[cur ^ 1][tid * 8]);
        gload16(VT + (size_t)(g * 64 + srow) * 4096 + b * 2048 + tn + sc * 8, &Vlds[cur ^ 1][tid * 8]);
      }

      if (t0 <= qw0 + 15) {
        const u16* Kc = Klds[cur];
        const u16* Vc = Vlds[cur];
        f32x4 s[4];
        __builtin_amdgcn_s_setprio(1);
#pragma unroll
        for (int ct = 0; ct < 4; ++ct) {
          int t = ct * 16 + l15;
          bf16x8 kf0 = *(const bf16x8*)&Kc[(t * 8 + (l4 ^ (t & 7))) * 8];
          bf16x8 kf1 = *(const bf16x8*)&Kc[(t * 8 + ((l4 + 4) ^ (t & 7))) * 8];
          f32x4 sv = {0.f, 0.f, 0.f, 0.f};
          sv = MFMA16(kf0, qf0, sv);   // swapped: S[t][q]
          sv = MFMA16(kf1, qf1, sv);
          s[ct] = sv;
        }
        __builtin_amdgcn_s_setprio(0);

        if (t0 + 63 > qw0) {
          const int qg = qw0 + l15;
#pragma unroll
          for (int ct = 0; ct < 4; ++ct)
#pragma unroll
            for (int e = 0; e < 4; ++e) {
              int tg = t0 + ct * 16 + l4 * 4 + e;
              if (tg > qg) s[ct][e] = -1e30f;
            }
        }

        float m0 = fmaxf(fmaxf(s[0][0], s[0][1]), fmaxf(s[0][2], s[0][3]));
        float m1 = fmaxf(fmaxf(s[1][0], s[1][1]), fmaxf(s[1][2], s[1][3]));
        float m2 = fmaxf(fmaxf(s[2][0], s[2][1]), fmaxf(s[2][2], s[2][3]));
        float m3 = fmaxf(fmaxf(s[3][0], s[3][1]), fmaxf(s[3][2], s[3][3]));
        float mt = fmaxf(fmaxf(m0, m1), fmaxf(m2, m3));
        mt = fmaxf(mt, __shfl_xor(mt, 16));
        mt = fmaxf(mt, __shfl_xor(mt, 32));

        if (!__all(mt <= m_r + 8.0f)) {
          float mn = fmaxf(m_r, mt);
          float alpha = __expf(m_r - mn);
          m_r = mn;
          l_r *= alpha;
#pragma unroll
          for (int e = 0; e < 4; ++e) {
            float ae = __shfl(alpha, l4 * 4 + e);
            o[0][e] *= ae; o[1][e] *= ae; o[2][e] *= ae; o[3][e] *= ae;
          }
        }

        u16* P = Plds[wave];
        float rs = 0.f;
#pragma unroll
        for (int ct = 0; ct < 4; ++ct) {
          u16x4 pk;
#pragma unroll
          for (int e = 0; e < 4; ++e) {
            float p = __expf(s[ct][e] - m_r);
            rs += p;
            pk[e] = f2bf_native(p);
          }
          int slot = (ct * 2 + (l4 >> 1)) ^ (l15 & 7);
          *(u16x4*)&P[l15 * 64 + slot * 8 + (l4 & 1) * 4] = pk;
        }
        rs += __shfl_xor(rs, 16);
        rs += __shfl_xor(rs, 32);
        l_r += rs;

        __builtin_amdgcn_s_setprio(1);
#pragma unroll
        for (int kk = 0; kk < 2; ++kk) {
          bf16x8 pf = *(const bf16x8*)&P[l15 * 64 + (((kk * 4 + l4) ^ (l15 & 7)) * 8)];
#pragma unroll
          for (int cd = 0; cd < 4; ++cd) {
            int d = cd * 16 + l15;
            bf16x8 vf = *(const bf16x8*)&Vc[(d * 8 + ((kk * 4 + l4) ^ (d & 7))) * 8];
            o[cd] = MFMA16(pf, vf, o[cd]);
          }
        }
        __builtin_amdgcn_s_setprio(0);
      }

      asm volatile("s_waitcnt vmcnt(0)" ::: "memory");
      __builtin_amdgcn_s_barrier();
      cur ^= 1;
    }

    float rli = 1.0f / l_r;
#pragma unroll
    for (int cd = 0; cd < 4; ++cd)
#pragma unroll
      for (int e = 0; e < 4; ++e) {
        float rle = __shfl(rli, l4 * 4 + e);
        int r = l4 * 4 + e;
        int d = cd * 16 + l15;
        AO[(size_t)(b * 2048 + qw0 + r) * 2048 + h * 64 + d] = f2bf_native(o[cd][e] * rle);
      }
  }
}

// ---------------- launcher ----------------
extern "C" void kernel_launch(void* const* d_in, const int* in_sizes, int n_in,
                              void* d_out, int out_size, void* d_ws, size_t ws_size,
                              hipStream_t stream) {
  const float* X  = (const float*)d_in[0];
  const float* Wq = (const float*)d_in[1];
  const float* Wk = (const float*)d_in[2];
  const float* Wv = (const float*)d_in[3];
  const float* Wo = (const float*)d_in[4];
  float* out = (float*)d_out;

  u16* ws  = (u16*)d_ws;
  u16* Xb  = ws;                 // 8,388,608 elems  [4096][2048]
  u16* WqT = Xb  + 8388608;      // 4,194,304  [2048][2048] -- WqT,WkT,WvT contiguous [3072][2048]
  u16* WkT = WqT + 4194304;      // 1,048,576  [512][2048]
  u16* WvT = WkT + 1048576;      // 1,048,576  [512][2048]
  u16* WoT = WvT + 1048576;      // 4,194,304  [2048][2048]
  u16* Qb  = WoT + 4194304;      // 8,388,608  [4096][2048]  (pre-scaled by 0.125)
  u16* Kbf = Qb  + 8388608;      // 2,097,152  [4096][512]
  u16* VTb = Kbf + 2097152;      // 2,097,152  [512][4096]
  u16* AOb = Xb;                 // alias X after projections are done

  // preamble: X cvt + Wq/Wk/Wv transposes (WoT rides under attn)
  preamble<<<dim3(64, 64, 4), dim3(32, 32), 0, stream>>>(X, Wq, Wk, Wv,
                                                         Xb, WqT, WkT, WvT);

  // fused QKV projection: BT = [WqT; WkT; WvT] (contiguous), N = 3072, grid 24x32 = 768 blocks
  gemm4<4><<<dim3(24, 32), 256, 0, stream>>>(Xb, WqT, Qb, 4096, 3072, 2048);

  // attention (z=0,1) + hidden WoT transpose (z=2)
  attn_fwd<<<dim3(32, 8, 3), 512, 0, stream>>>(Qb, Kbf, VTb, AOb, Wo, WoT);

  // output projection: grid 16x32 = 512 blocks (measured best for Wo)
  gemm4<2><<<dim3(16, 32), 256, 0, stream>>>(AOb, WoT, out, 4096, 2048, 2048);
}